// Round 6
// baseline (361.933 us; speedup 1.0000x reference)
//
#include <hip/hip_runtime.h>
#include <hip/hip_bf16.h>

// SpatialTransformer: 3D trilinear warp, zeros padding.
// src [B,C,D,H,W] f32 = [2,2,128,160,128]; flow [B,3,D,H,W]; out [B,C,D,H,W].
//
// R6: R3 body (256 threads, 52 VGPR, no spill) + SMALLER LDS tile to raise
// the occupancy cap: out 16x8x8, y/z halo 3, x halo 4 -> cached 14x14x24 f32
// = 18.4 KB -> 8 blocks/CU x 4 waves = 32 waves/CU (R3: 16).
// R4/R5 lesson: 512-thread variants spill to scratch (+260..+430 MB phantom
// traffic). Never carry private arrays across barriers; keep 256 threads.
// Fallback (outside halo window): ~0.1% of voxels, exact global gather.

#define B_ 2
#define C_ 2
#define D_ 128
#define H_ 160
#define W_ 128
constexpr int S_ = D_ * H_ * W_;

#define ZT 8
#define YT 8
#define XT 16
#define RZ 3
#define RY 3
#define RX 4
#define CZ (ZT + 2 * RZ)   // 14
#define CY (YT + 2 * RY)   // 14
#define CX (XT + 2 * RX)   // 24
#define NTHREADS 256
#define VPT 4              // voxels per thread per channel (1024/256)
#define NCHUNK (CZ * CY * (CX / 4))   // 1176 float4 staging chunks

__device__ __forceinline__ float pair_val(const float* p, bool hi0, bool lo1,
                                          float wx0, float wx1) {
    const float v0 = hi0 ? p[1] : p[0];
    const float v1 = lo1 ? p[0] : p[1];
    return wx0 * v0 + wx1 * v1;
}

__global__ __launch_bounds__(NTHREADS, 8) void warp3d_tile(
    const float* __restrict__ src,
    const float* __restrict__ flow,
    float* __restrict__ out)
{
    __shared__ float tile[CZ * CY * CX];   // 4704 floats = 18.4 KB

    const int tid = threadIdx.x;
    const int xb = blockIdx.x * XT;
    const int yb = blockIdx.y * YT;
    const int zb = (blockIdx.z & 15) * ZT;
    const int b  = blockIdx.z >> 4;

    const int zlo = max(0, zb - RZ), zhi = min(D_, zb + ZT + RZ);
    const int ylo = max(0, yb - RY), yhi = min(H_, yb + YT + RY);
    const int xlo = max(0, xb - RX), xhi = min(W_, xb + XT + RX);

    const float* fb = flow + (long long)b * 3 * S_;

    for (int ch = 0; ch < C_; ++ch) {
        const float* sc = src + ((long long)b * C_ + ch) * S_;
        float* oc       = out + ((long long)b * C_ + ch) * S_;

        if (ch) __syncthreads();           // tile reads done before restage

        // ---- stage src tile (+halo): 1176 float4 chunks, <=5 per thread ----
#pragma unroll
        for (int j = 0; j < 5; ++j) {
            const int lin = j * NTHREADS + tid;
            if (lin < NCHUNK) {
                const int row = lin / 6;               // 0..195  (rz*CY+ry)
                const int c   = lin - row * 6;         // 0..5
                const int rz = row / CY, ry = row - rz * CY;
                const int gz = zb - RZ + rz;
                const int gy = yb - RY + ry;
                const int gx = xb - RX + c * 4;        // multiple of 4
                if ((unsigned)gz < (unsigned)D_ && (unsigned)gy < (unsigned)H_ &&
                    (unsigned)gx <= (unsigned)(W_ - 4)) {
                    const float4 v = *(const float4*)(sc + ((gz * H_ + gy) << 7) + gx);
                    *(float4*)&tile[row * CX + c * 4] = v;
                }
            }
        }
        __syncthreads();

        // ---- compute: 1024 voxels, 4 per thread ----
#pragma unroll
        for (int it = 0; it < VPT; ++it) {
            const int vox = it * NTHREADS + tid;
            const int lx = vox & 15, ly = (vox >> 4) & 7, lz = vox >> 7;
            const int x = xb + lx, y = yb + ly, z = zb + lz;
            const int s = ((z * H_ + y) << 7) + x;

            const float fz = fb[s], fy = fb[S_ + s], fx = fb[2 * S_ + s];
            const float iz = (float)z + fz;
            const float iy = (float)y + fy;
            const float ix = (float)x + fx;

            const float zf = floorf(iz), yf = floorf(iy), xf = floorf(ix);
            const float tz = iz - zf, ty = iy - yf, tx = ix - xf;
            const int z0 = (int)zf, y0 = (int)yf, x0 = (int)xf;

            const int zc0 = min(max(z0, 0), D_ - 1), zc1 = min(max(z0 + 1, 0), D_ - 1);
            const int yc0 = min(max(y0, 0), H_ - 1), yc1 = min(max(y0 + 1, 0), H_ - 1);
            const int xp  = min(max(x0, 0), W_ - 2);

            const float wz0 = ((unsigned)z0       < (unsigned)D_) ? (1.f - tz) : 0.f;
            const float wz1 = ((unsigned)(z0 + 1) < (unsigned)D_) ? tz         : 0.f;
            const float wy0 = ((unsigned)y0       < (unsigned)H_) ? (1.f - ty) : 0.f;
            const float wy1 = ((unsigned)(y0 + 1) < (unsigned)H_) ? ty         : 0.f;
            const float wx0 = ((unsigned)x0       < (unsigned)W_) ? (1.f - tx) : 0.f;
            const float wx1 = ((unsigned)(x0 + 1) < (unsigned)W_) ? tx         : 0.f;
            const bool hi0 = x0 > xp;   // x0 == W-1
            const bool lo1 = x0 < xp;   // x0 == -1

            const bool fast = (zc0 >= zlo) & (zc1 < zhi) &
                              (yc0 >= ylo) & (yc1 < yhi) &
                              (xp >= xlo) & (xp + 1 < xhi);

            float acc;
            if (fast) {
                const int izl0 = zc0 - (zb - RZ), izl1 = zc1 - (zb - RZ);
                const int iyl0 = yc0 - (yb - RY), iyl1 = yc1 - (yb - RY);
                const int ixl  = xp - (xb - RX);
                const float* t00 = &tile[(izl0 * CY + iyl0) * CX + ixl];
                const float* t01 = &tile[(izl0 * CY + iyl1) * CX + ixl];
                const float* t10 = &tile[(izl1 * CY + iyl0) * CX + ixl];
                const float* t11 = &tile[(izl1 * CY + iyl1) * CX + ixl];
                const float p00 = pair_val(t00, hi0, lo1, wx0, wx1);
                const float p01 = pair_val(t01, hi0, lo1, wx0, wx1);
                const float p10 = pair_val(t10, hi0, lo1, wx0, wx1);
                const float p11 = pair_val(t11, hi0, lo1, wx0, wx1);
                acc = wz0 * (wy0 * p00 + wy1 * p01) + wz1 * (wy0 * p10 + wy1 * p11);
            } else {
                const float* g00 = sc + ((zc0 * H_ + yc0) << 7) + xp;
                const float* g01 = sc + ((zc0 * H_ + yc1) << 7) + xp;
                const float* g10 = sc + ((zc1 * H_ + yc0) << 7) + xp;
                const float* g11 = sc + ((zc1 * H_ + yc1) << 7) + xp;
                const float p00 = pair_val(g00, hi0, lo1, wx0, wx1);
                const float p01 = pair_val(g01, hi0, lo1, wx0, wx1);
                const float p10 = pair_val(g10, hi0, lo1, wx0, wx1);
                const float p11 = pair_val(g11, hi0, lo1, wx0, wx1);
                acc = wz0 * (wy0 * p00 + wy1 * p01) + wz1 * (wy0 * p10 + wy1 * p11);
            }
            oc[s] = acc;
        }
    }
}

extern "C" void kernel_launch(void* const* d_in, const int* in_sizes, int n_in,
                              void* d_out, int out_size, void* d_ws, size_t ws_size,
                              hipStream_t stream) {
    const float* src  = (const float*)d_in[0];
    const float* flow = (const float*)d_in[1];
    float* out = (float*)d_out;

    dim3 grid(W_ / XT, H_ / YT, (D_ / ZT) * B_);   // 8 x 20 x 32 = 5120 blocks
    warp3d_tile<<<grid, NTHREADS, 0, stream>>>(src, flow, out);
}

// Round 7
// 254.948 us; speedup vs baseline: 1.4196x; 1.4196x over previous
//
#include <hip/hip_runtime.h>
#include <hip/hip_bf16.h>

// SpatialTransformer: 3D trilinear warp, zeros padding.
// src [B,C,D,H,W] f32 = [2,2,128,160,128]; flow [B,3,D,H,W]; out [B,C,D,H,W].
//
// R7: R6's small tile (out 16x8x8, halo z/y=3 x=4, cached 14x14x24 = 18.4 KB
// -> 8 blocks/CU) with __launch_bounds__(256,4). R5/R6 lesson: a tight
// launch_bounds VGPR cap (min-waves 8 -> 64 VGPR budget) makes the allocator
// collapse to 32 VGPR + wholesale scratch spill (+460 MB phantom writes).
// (256,4) -> 128 VGPR budget; body fits at ~52 VGPR, no spill; HW occupancy
// then LDS-limited at 8 blocks/CU = 32 waves/CU (2x R3's 16).
// Fallback (outside halo window): ~0.1% of voxels, exact global gather.

#define B_ 2
#define C_ 2
#define D_ 128
#define H_ 160
#define W_ 128
constexpr int S_ = D_ * H_ * W_;

#define ZT 8
#define YT 8
#define XT 16
#define RZ 3
#define RY 3
#define RX 4
#define CZ (ZT + 2 * RZ)   // 14
#define CY (YT + 2 * RY)   // 14
#define CX (XT + 2 * RX)   // 24
#define NTHREADS 256
#define VPT 4              // voxels per thread per channel (1024/256)
#define NCHUNK (CZ * CY * (CX / 4))   // 1176 float4 staging chunks

__device__ __forceinline__ float pair_val(const float* p, bool hi0, bool lo1,
                                          float wx0, float wx1) {
    const float v0 = hi0 ? p[1] : p[0];
    const float v1 = lo1 ? p[0] : p[1];
    return wx0 * v0 + wx1 * v1;
}

__global__ __launch_bounds__(NTHREADS, 4) void warp3d_tile(
    const float* __restrict__ src,
    const float* __restrict__ flow,
    float* __restrict__ out)
{
    __shared__ float tile[CZ * CY * CX];   // 4704 floats = 18.4 KB

    const int tid = threadIdx.x;
    const int xb = blockIdx.x * XT;
    const int yb = blockIdx.y * YT;
    const int zb = (blockIdx.z & 15) * ZT;
    const int b  = blockIdx.z >> 4;

    const int zlo = max(0, zb - RZ), zhi = min(D_, zb + ZT + RZ);
    const int ylo = max(0, yb - RY), yhi = min(H_, yb + YT + RY);
    const int xlo = max(0, xb - RX), xhi = min(W_, xb + XT + RX);

    const float* fb = flow + (long long)b * 3 * S_;

    for (int ch = 0; ch < C_; ++ch) {
        const float* sc = src + ((long long)b * C_ + ch) * S_;
        float* oc       = out + ((long long)b * C_ + ch) * S_;

        if (ch) __syncthreads();           // tile reads done before restage

        // ---- stage src tile (+halo): 1176 float4 chunks, <=5 per thread ----
#pragma unroll
        for (int j = 0; j < 5; ++j) {
            const int lin = j * NTHREADS + tid;
            if (lin < NCHUNK) {
                const int row = lin / 6;               // 0..195  (rz*CY+ry)
                const int c   = lin - row * 6;         // 0..5
                const int rz = row / CY, ry = row - rz * CY;
                const int gz = zb - RZ + rz;
                const int gy = yb - RY + ry;
                const int gx = xb - RX + c * 4;        // multiple of 4
                if ((unsigned)gz < (unsigned)D_ && (unsigned)gy < (unsigned)H_ &&
                    (unsigned)gx <= (unsigned)(W_ - 4)) {
                    const float4 v = *(const float4*)(sc + ((gz * H_ + gy) << 7) + gx);
                    *(float4*)&tile[row * CX + c * 4] = v;
                }
            }
        }
        __syncthreads();

        // ---- compute: 1024 voxels, 4 per thread ----
#pragma unroll
        for (int it = 0; it < VPT; ++it) {
            const int vox = it * NTHREADS + tid;
            const int lx = vox & 15, ly = (vox >> 4) & 7, lz = vox >> 7;
            const int x = xb + lx, y = yb + ly, z = zb + lz;
            const int s = ((z * H_ + y) << 7) + x;

            const float fz = fb[s], fy = fb[S_ + s], fx = fb[2 * S_ + s];
            const float iz = (float)z + fz;
            const float iy = (float)y + fy;
            const float ix = (float)x + fx;

            const float zf = floorf(iz), yf = floorf(iy), xf = floorf(ix);
            const float tz = iz - zf, ty = iy - yf, tx = ix - xf;
            const int z0 = (int)zf, y0 = (int)yf, x0 = (int)xf;

            const int zc0 = min(max(z0, 0), D_ - 1), zc1 = min(max(z0 + 1, 0), D_ - 1);
            const int yc0 = min(max(y0, 0), H_ - 1), yc1 = min(max(y0 + 1, 0), H_ - 1);
            const int xp  = min(max(x0, 0), W_ - 2);

            const float wz0 = ((unsigned)z0       < (unsigned)D_) ? (1.f - tz) : 0.f;
            const float wz1 = ((unsigned)(z0 + 1) < (unsigned)D_) ? tz         : 0.f;
            const float wy0 = ((unsigned)y0       < (unsigned)H_) ? (1.f - ty) : 0.f;
            const float wy1 = ((unsigned)(y0 + 1) < (unsigned)H_) ? ty         : 0.f;
            const float wx0 = ((unsigned)x0       < (unsigned)W_) ? (1.f - tx) : 0.f;
            const float wx1 = ((unsigned)(x0 + 1) < (unsigned)W_) ? tx         : 0.f;
            const bool hi0 = x0 > xp;   // x0 == W-1
            const bool lo1 = x0 < xp;   // x0 == -1

            const bool fast = (zc0 >= zlo) & (zc1 < zhi) &
                              (yc0 >= ylo) & (yc1 < yhi) &
                              (xp >= xlo) & (xp + 1 < xhi);

            float acc;
            if (fast) {
                const int izl0 = zc0 - (zb - RZ), izl1 = zc1 - (zb - RZ);
                const int iyl0 = yc0 - (yb - RY), iyl1 = yc1 - (yb - RY);
                const int ixl  = xp - (xb - RX);
                const float* t00 = &tile[(izl0 * CY + iyl0) * CX + ixl];
                const float* t01 = &tile[(izl0 * CY + iyl1) * CX + ixl];
                const float* t10 = &tile[(izl1 * CY + iyl0) * CX + ixl];
                const float* t11 = &tile[(izl1 * CY + iyl1) * CX + ixl];
                const float p00 = pair_val(t00, hi0, lo1, wx0, wx1);
                const float p01 = pair_val(t01, hi0, lo1, wx0, wx1);
                const float p10 = pair_val(t10, hi0, lo1, wx0, wx1);
                const float p11 = pair_val(t11, hi0, lo1, wx0, wx1);
                acc = wz0 * (wy0 * p00 + wy1 * p01) + wz1 * (wy0 * p10 + wy1 * p11);
            } else {
                const float* g00 = sc + ((zc0 * H_ + yc0) << 7) + xp;
                const float* g01 = sc + ((zc0 * H_ + yc1) << 7) + xp;
                const float* g10 = sc + ((zc1 * H_ + yc0) << 7) + xp;
                const float* g11 = sc + ((zc1 * H_ + yc1) << 7) + xp;
                const float p00 = pair_val(g00, hi0, lo1, wx0, wx1);
                const float p01 = pair_val(g01, hi0, lo1, wx0, wx1);
                const float p10 = pair_val(g10, hi0, lo1, wx0, wx1);
                const float p11 = pair_val(g11, hi0, lo1, wx0, wx1);
                acc = wz0 * (wy0 * p00 + wy1 * p01) + wz1 * (wy0 * p10 + wy1 * p11);
            }
            oc[s] = acc;
        }
    }
}

extern "C" void kernel_launch(void* const* d_in, const int* in_sizes, int n_in,
                              void* d_out, int out_size, void* d_ws, size_t ws_size,
                              hipStream_t stream) {
    const float* src  = (const float*)d_in[0];
    const float* flow = (const float*)d_in[1];
    float* out = (float*)d_out;

    dim3 grid(W_ / XT, H_ / YT, (D_ / ZT) * B_);   // 8 x 20 x 32 = 5120 blocks
    warp3d_tile<<<grid, NTHREADS, 0, stream>>>(src, flow, out);
}

// Round 8
// 163.760 us; speedup vs baseline: 2.2102x; 1.5568x over previous
//
#include <hip/hip_runtime.h>
#include <hip/hip_bf16.h>

// SpatialTransformer: 3D trilinear warp, zeros padding.
// src [B,C,D,H,W] f32 = [2,2,128,160,128]; flow [B,3,D,H,W]; out [B,C,D,H,W].
//
// R8: raise occupancy WITHOUT breaking line granularity.
//  - R7 lesson: XT=16 -> 64 B chunks split across XCDs -> 2x fetch / 4x write
//    amplification. Keep XT=32 (full 128 B lines everywhere).
//  - Shrink Z instead: out tile 32x8x4, halo z/y=3 x=4 -> cached 10x14x40 f32
//    = 21.9 KB LDS -> 7 blocks/CU x 4 waves = 28 waves/CU (R3 had 16).
//  - Channel moved into the grid (blockIdx.z encodes z-tile, batch, channel):
//    single stage+compute phase per block.
//  - R5/R6 lesson: tight launch_bounds caps trigger catastrophic spill; use
//    (256,4) = 128 VGPR budget (body needs ~52-64).
// Fallback (outside halo window): ~0.1% of voxels, exact global gather.

#define B_ 2
#define C_ 2
#define D_ 128
#define H_ 160
#define W_ 128
constexpr int S_ = D_ * H_ * W_;

#define ZT 4
#define YT 8
#define XT 32
#define RZ 3
#define RY 3
#define RX 4
#define CZ (ZT + 2 * RZ)   // 10
#define CY (YT + 2 * RY)   // 14
#define CX (XT + 2 * RX)   // 40
#define NTHREADS 256
#define VPT ((ZT * YT * XT) / NTHREADS)        // 4 voxels per thread
#define NCHUNK (CZ * CY * (CX / 4))            // 1400 float4 staging chunks

__device__ __forceinline__ float pair_val(const float* p, bool hi0, bool lo1,
                                          float wx0, float wx1) {
    const float v0 = hi0 ? p[1] : p[0];
    const float v1 = lo1 ? p[0] : p[1];
    return wx0 * v0 + wx1 * v1;
}

__global__ __launch_bounds__(NTHREADS, 4) void warp3d_tile(
    const float* __restrict__ src,
    const float* __restrict__ flow,
    float* __restrict__ out)
{
    __shared__ float tile[CZ * CY * CX];   // 5600 floats = 21.9 KB

    const int tid = threadIdx.x;
    const int xb = blockIdx.x * XT;
    const int yb = blockIdx.y * YT;
    const int bz = blockIdx.z;
    const int zb = (bz & 31) * ZT;         // 32 z-tiles
    const int b  = (bz >> 6);              // bit 6: batch
    const int ch = (bz >> 5) & 1;          // bit 5: channel

    const int zlo = max(0, zb - RZ), zhi = min(D_, zb + ZT + RZ);
    const int ylo = max(0, yb - RY), yhi = min(H_, yb + YT + RY);
    const int xlo = max(0, xb - RX), xhi = min(W_, xb + XT + RX);

    const float* fb = flow + (long long)b * 3 * S_;
    const float* sc = src + ((long long)b * C_ + ch) * S_;
    float* oc       = out + ((long long)b * C_ + ch) * S_;

    // ---- stage src tile (+halo): 1400 float4 chunks, <=6 per thread ----
#pragma unroll
    for (int j = 0; j < 6; ++j) {
        const int lin = j * NTHREADS + tid;
        if (lin < NCHUNK) {
            const int row = lin / 10;              // 0..139  (rz*CY+ry)
            const int c   = lin - row * 10;        // 0..9
            const int rz = row / CY, ry = row - rz * CY;
            const int gz = zb - RZ + rz;
            const int gy = yb - RY + ry;
            const int gx = xb - RX + c * 4;        // multiple of 4
            if ((unsigned)gz < (unsigned)D_ && (unsigned)gy < (unsigned)H_ &&
                (unsigned)gx <= (unsigned)(W_ - 4)) {
                const float4 v = *(const float4*)(sc + ((gz * H_ + gy) << 7) + gx);
                *(float4*)&tile[row * CX + c * 4] = v;
            }
        }
    }
    __syncthreads();

    // ---- compute: 1024 voxels, 4 per thread ----
#pragma unroll
    for (int it = 0; it < VPT; ++it) {
        const int vox = it * NTHREADS + tid;
        const int lx = vox & 31, ly = (vox >> 5) & 7, lz = vox >> 8;
        const int x = xb + lx, y = yb + ly, z = zb + lz;
        const int s = ((z * H_ + y) << 7) + x;

        const float fz = fb[s], fy = fb[S_ + s], fx = fb[2 * S_ + s];
        const float iz = (float)z + fz;
        const float iy = (float)y + fy;
        const float ix = (float)x + fx;

        const float zf = floorf(iz), yf = floorf(iy), xf = floorf(ix);
        const float tz = iz - zf, ty = iy - yf, tx = ix - xf;
        const int z0 = (int)zf, y0 = (int)yf, x0 = (int)xf;

        const int zc0 = min(max(z0, 0), D_ - 1), zc1 = min(max(z0 + 1, 0), D_ - 1);
        const int yc0 = min(max(y0, 0), H_ - 1), yc1 = min(max(y0 + 1, 0), H_ - 1);
        const int xp  = min(max(x0, 0), W_ - 2);

        const float wz0 = ((unsigned)z0       < (unsigned)D_) ? (1.f - tz) : 0.f;
        const float wz1 = ((unsigned)(z0 + 1) < (unsigned)D_) ? tz         : 0.f;
        const float wy0 = ((unsigned)y0       < (unsigned)H_) ? (1.f - ty) : 0.f;
        const float wy1 = ((unsigned)(y0 + 1) < (unsigned)H_) ? ty         : 0.f;
        const float wx0 = ((unsigned)x0       < (unsigned)W_) ? (1.f - tx) : 0.f;
        const float wx1 = ((unsigned)(x0 + 1) < (unsigned)W_) ? tx         : 0.f;
        const bool hi0 = x0 > xp;   // x0 == W-1
        const bool lo1 = x0 < xp;   // x0 == -1

        const bool fast = (zc0 >= zlo) & (zc1 < zhi) &
                          (yc0 >= ylo) & (yc1 < yhi) &
                          (xp >= xlo) & (xp + 1 < xhi);

        float acc;
        if (fast) {
            const int izl0 = zc0 - (zb - RZ), izl1 = zc1 - (zb - RZ);
            const int iyl0 = yc0 - (yb - RY), iyl1 = yc1 - (yb - RY);
            const int ixl  = xp - (xb - RX);
            const float* t00 = &tile[(izl0 * CY + iyl0) * CX + ixl];
            const float* t01 = &tile[(izl0 * CY + iyl1) * CX + ixl];
            const float* t10 = &tile[(izl1 * CY + iyl0) * CX + ixl];
            const float* t11 = &tile[(izl1 * CY + iyl1) * CX + ixl];
            const float p00 = pair_val(t00, hi0, lo1, wx0, wx1);
            const float p01 = pair_val(t01, hi0, lo1, wx0, wx1);
            const float p10 = pair_val(t10, hi0, lo1, wx0, wx1);
            const float p11 = pair_val(t11, hi0, lo1, wx0, wx1);
            acc = wz0 * (wy0 * p00 + wy1 * p01) + wz1 * (wy0 * p10 + wy1 * p11);
        } else {
            const float* g00 = sc + ((zc0 * H_ + yc0) << 7) + xp;
            const float* g01 = sc + ((zc0 * H_ + yc1) << 7) + xp;
            const float* g10 = sc + ((zc1 * H_ + yc0) << 7) + xp;
            const float* g11 = sc + ((zc1 * H_ + yc1) << 7) + xp;
            const float p00 = pair_val(g00, hi0, lo1, wx0, wx1);
            const float p01 = pair_val(g01, hi0, lo1, wx0, wx1);
            const float p10 = pair_val(g10, hi0, lo1, wx0, wx1);
            const float p11 = pair_val(g11, hi0, lo1, wx0, wx1);
            acc = wz0 * (wy0 * p00 + wy1 * p01) + wz1 * (wy0 * p10 + wy1 * p11);
        }
        oc[s] = acc;
    }
}

extern "C" void kernel_launch(void* const* d_in, const int* in_sizes, int n_in,
                              void* d_out, int out_size, void* d_ws, size_t ws_size,
                              hipStream_t stream) {
    const float* src  = (const float*)d_in[0];
    const float* flow = (const float*)d_in[1];
    float* out = (float*)d_out;

    // grid: x 4, y 20, z = 32 z-tiles x C2 x B2 = 128  -> 10240 blocks
    dim3 grid(W_ / XT, H_ / YT, (D_ / ZT) * C_ * B_);
    warp3d_tile<<<grid, NTHREADS, 0, stream>>>(src, flow, out);
}